// Round 7
// baseline (757.962 us; speedup 1.0000x reference)
//
#include <hip/hip_runtime.h>
#include <stdint.h>
#include <math.h>

#define NTOK 2048
#define HDIM 2048
#define FDIM 1024
#define NEXP 32
#define TOPK 4
#define NGRP 4
#define CAP  512

typedef _Float16 f16;
typedef _Float16 half8 __attribute__((ext_vector_type(8)));
typedef float f32x4 __attribute__((ext_vector_type(4)));

// ---------------- convert x fp32 [2048][2048] -> xbt fp16 k-chunked [64][2048][32] ----------------
__global__ __launch_bounds__(256) void convert_kernel(const float* __restrict__ x,
                                                      f16* __restrict__ xbt) {
  int i = blockIdx.x * 256 + threadIdx.x;
  int r = i >> 8;
  int c8 = (i & 255) << 3;
  const float* p = x + (size_t)r * HDIM + c8;
  f32x4 a = *(const f32x4*)p;
  f32x4 b = *(const f32x4*)(p + 4);
  half8 v;
  v[0] = (f16)a[0]; v[1] = (f16)a[1]; v[2] = (f16)a[2]; v[3] = (f16)a[3];
  v[4] = (f16)b[0]; v[5] = (f16)b[1]; v[6] = (f16)b[2]; v[7] = (f16)b[3];
  int t = c8 >> 5;
  *(half8*)((char*)xbt + (size_t)t * 131072 + r * 64 + (c8 & 31) * 2) = v;
}

// ---------------- gate ----------------
__global__ __launch_bounds__(256) void gate_kernel(const float* __restrict__ x,
                                                   const float* __restrict__ gw,
                                                   const float* __restrict__ gb,
                                                   int* __restrict__ tidx,
                                                   float* __restrict__ tw) {
  int t = blockIdx.x;
  int tid = threadIdx.x;
  int e = tid >> 3, p = tid & 7;
  const f32x4* xr = (const f32x4*)(x + (size_t)t * HDIM);
  const f32x4* wr = (const f32x4*)(gw + (size_t)e * HDIM);
  float s = 0.f;
  for (int c = 0; c < 64; c++) {
    f32x4 a = xr[p + c * 8], w = wr[p + c * 8];
    s += a[0] * w[0] + a[1] * w[1] + a[2] * w[2] + a[3] * w[3];
  }
  s += __shfl_down(s, 4, 8);
  s += __shfl_down(s, 2, 8);
  s += __shfl_down(s, 1, 8);
  __shared__ float lg[NEXP];
  if (p == 0) lg[e] = s;
  __syncthreads();
  if (tid == 0) {
    float sc[NEXP], scb[NEXP];
    for (int i = 0; i < NEXP; i++) {
      sc[i] = 1.f / (1.f + expf(-lg[i]));
      scb[i] = sc[i] + gb[i];
    }
    float gs[NGRP];
    for (int g = 0; g < NGRP; g++) {
      float m1 = -1e30f, m2 = -1e30f;
      for (int j = 0; j < 8; j++) {
        float v = scb[g * 8 + j];
        if (v > m1) { m2 = m1; m1 = v; }
        else if (v > m2) m2 = v;
      }
      gs[g] = m1 + m2;
    }
    int g1 = 0; float bv = gs[0];
    for (int g = 1; g < NGRP; g++) if (gs[g] > bv) { bv = gs[g]; g1 = g; }
    int g2 = -1; bv = -1e30f;
    for (int g = 0; g < NGRP; g++) if (g != g1 && gs[g] > bv) { bv = gs[g]; g2 = g; }
    float cand[NEXP];
    for (int i = 0; i < NEXP; i++) {
      int g = i >> 3;
      cand[i] = (g == g1 || g == g2) ? scb[i] : 0.0f;
    }
    int isel[TOPK]; float wsel[TOPK]; float wsum = 0.f;
    bool used[NEXP] = {};
    for (int k = 0; k < TOPK; k++) {
      int best = 0; float bw = -1e30f;
      for (int i = 0; i < NEXP; i++)
        if (!used[i] && cand[i] > bw) { bw = cand[i]; best = i; }
      used[best] = true;
      isel[k] = best;
      wsel[k] = sc[best];
      wsum += wsel[k];
    }
    float inv = 2.0f / (wsum + 1e-20f);
    for (int k = 0; k < TOPK; k++) {
      tidx[t * TOPK + k] = isel[k];
      tw[t * TOPK + k] = wsel[k] * inv;
    }
  }
}

// ---------------- dispatch ----------------
__global__ __launch_bounds__(256) void dispatch_kernel(const int* __restrict__ tidx,
                                                       const float* __restrict__ tw,
                                                       int* __restrict__ tok,
                                                       float* __restrict__ wt,
                                                       int* __restrict__ cnt) {
  int e = blockIdx.x, tid = threadIdx.x, wv = tid >> 6, lane = tid & 63;
  __shared__ int wsum[4];
  __shared__ int sbase;
  if (tid == 0) sbase = 0;
  __syncthreads();
  for (int c = 0; c < (NTOK * TOPK) / 256; c++) {
    int i = c * 256 + tid;
    int fe = tidx[i];
    bool flag = (fe == e);
    unsigned long long b = __ballot(flag ? 1 : 0);
    int lr = __popcll(b & ((1ull << lane) - 1ull));
    if (lane == 0) wsum[wv] = __popcll(b);
    __syncthreads();
    int off = 0;
    for (int w2 = 0; w2 < wv; w2++) off += wsum[w2];
    int tot = wsum[0] + wsum[1] + wsum[2] + wsum[3];
    int base = sbase;
    if (flag) {
      int pos = base + off + lr;
      if (pos < CAP) {
        tok[e * CAP + pos] = i >> 2;
        wt[e * CAP + pos] = tw[i];
      }
    }
    __syncthreads();
    if (tid == 0) sbase = base + tot;
  }
  __syncthreads();
  if (tid == 0) cnt[e] = min(sbase, CAP);
}

// ---------------- gather: xg[e][t][slot][32k] = xbt[t][tok[e][slot]], zero-padded ----------------
__global__ __launch_bounds__(256) void gather_kernel(const f16* __restrict__ xbt,
                                                     const int* __restrict__ tok,
                                                     const int* __restrict__ cnt,
                                                     f16* __restrict__ xg) {
  int bid = blockIdx.x;
  int t = bid & 63, e = bid >> 6;
  int cn = cnt[e];
  int tid = threadIdx.x;
  char* dst = (char*)xg + (size_t)e * 2097152 + (size_t)t * 32768;
  const char* srcb = (const char*)xbt + (size_t)t * 131072;
  for (int s = tid; s < CAP; s += 256) {
    uint4 v0 = {0,0,0,0}, v1 = {0,0,0,0}, v2 = {0,0,0,0}, v3 = {0,0,0,0};
    if (s < cn) {
      const uint4* sp = (const uint4*)(srcb + (size_t)tok[e * CAP + s] * 64);
      v0 = sp[0]; v1 = sp[1]; v2 = sp[2]; v3 = sp[3];
    }
    uint4* dp = (uint4*)(dst + s * 64);
    dp[0] = v0; dp[1] = v1; dp[2] = v2; dp[3] = v3;
  }
}

// ---------------- barrier-free all-register MFMA GEMM ----------------
// Both operands stream global->VGPR as MFMA fragments. No LDS, no barriers.
// B fp32 weights: 8 dword loads per fragment (lane map k=8q+i, col=lane&15),
// cvt to fp16 in regs. A fp16 k-chunked: b128 per fragment, double-buffered.
// MODE 0: routed up (dual w1/w3, A=xg[e], silu-mul -> hbuf k-chunked)
// MODE 1: shared up (dual sg/su, A=xbt, -> hs k-chunked)
// MODE 2: routed down (w2, A=hbuf[e], atomicAdd out)
// MODE 3: shared down (sd, A=hs, plain store out)
template<int MODE>
__global__ __launch_bounds__(256, (MODE <= 1) ? 2 : 3)
void gemm_kernel(const f16* __restrict__ Ag, const float* __restrict__ B0g,
                 const float* __restrict__ B1g, void* __restrict__ outp,
                 const int* __restrict__ tokL, const float* __restrict__ wtL,
                 const int* __restrict__ cntP) {
  constexpr bool DUAL = (MODE <= 1);
  constexpr bool ROUTED = (MODE == 0 || MODE == 2);
  constexpr int WM = ROUTED ? 128 : 64;     // rows per wave
  constexpr int MF = WM / 16;
  constexpr int NF = 2;                     // BN = 32
  constexpr int KD = (MODE == 2) ? 1024 : 2048;
  constexpr int NK = KD / 32;
  constexpr int ND = (MODE == 0) ? 1024 : 2048;
  constexpr size_t TS = ROUTED ? 32768 : 131072;  // A k-chunk byte stride

  int bid = blockIdx.x;
  int tid = threadIdx.x, lane = tid & 63, wv = tid >> 6;

  int e = 0, m0 = 0, n0 = 0;
  if constexpr (ROUTED) {
    e = bid & 31;              // bid%8 == e%8 -> same-expert blocks share XCD L2
    n0 = (bid >> 5) * 32;
  } else {
    m0 = (bid & 7) * 256;      // same-m blocks share XCD (A slice L2-hot)
    n0 = (bid >> 3) * 32;
  }

  const char* Ab = (const char*)Ag;
  const float* B0 = B0g;
  const float* B1 = B1g;
  int Mcur = NTOK;
  if constexpr (ROUTED) {
    Mcur = cntP[e];
    int Mpad = (Mcur + 127) & ~127;
    if (wv * 128 >= Mpad) return;     // dead wave: no LDS/barrier, safe to exit
    Ab += (size_t)e * ((MODE == 0) ? 2097152 : 1048576);
    B0 += (size_t)e * ((size_t)KD * ND);
    if constexpr (DUAL) B1 += (size_t)e * ((size_t)KD * ND);
  }

  // A fragment byte offsets within a k-chunk
  unsigned aoff[MF];
#pragma unroll
  for (int mf = 0; mf < MF; mf++) {
    int row = (ROUTED ? wv * WM : m0 + wv * WM) + mf * 16 + (lane & 15);
    aoff[mf] = row * 64 + ((lane >> 4) << 4);
  }

  int q8 = (lane >> 4) * 8;
  int nc = n0 + (lane & 15);

  float bst0[NF][8];
  float bst1[DUAL ? NF : 1][8];
  half8 bc0[NF];
  half8 bc1[DUAL ? NF : 1];
  half8 afA[MF], afB[MF];
  f32x4 acc0[MF][NF];
  f32x4 acc1[DUAL ? MF : 1][DUAL ? NF : 1];
#pragma unroll
  for (int mf = 0; mf < MF; mf++)
#pragma unroll
    for (int f = 0; f < NF; f++) acc0[mf][f] = (f32x4){0.f, 0.f, 0.f, 0.f};
  if constexpr (DUAL) {
#pragma unroll
    for (int mf = 0; mf < MF; mf++)
#pragma unroll
      for (int f = 0; f < NF; f++) acc1[mf][f] = (f32x4){0.f, 0.f, 0.f, 0.f};
  }

  auto loadB = [&](int t) {
#pragma unroll
    for (int i = 0; i < 8; i++) {
      size_t ro = (size_t)(t * 32 + q8 + i) * ND + nc;
      bst0[0][i] = B0[ro];
      bst0[1][i] = B0[ro + 16];
      if constexpr (DUAL) {
        bst1[0][i] = B1[ro];
        bst1[1][i] = B1[ro + 16];
      }
    }
  };
  auto cvtB = [&]() {
#pragma unroll
    for (int f = 0; f < NF; f++)
#pragma unroll
      for (int i = 0; i < 8; i++) {
        bc0[f][i] = (f16)bst0[f][i];
        if constexpr (DUAL) bc1[f][i] = (f16)bst1[f][i];
      }
  };

#define LOADAF(t, AF) { \
  _Pragma("unroll") \
  for (int mf = 0; mf < MF; mf++) \
    AF[mf] = *(const half8*)(Ab + (size_t)(t) * TS + aoff[mf]); }

#define DOMFMA(AF) { \
  _Pragma("unroll") \
  for (int mf = 0; mf < MF; mf++) { \
    _Pragma("unroll") \
    for (int f = 0; f < NF; f++) { \
      acc0[mf][f] = __builtin_amdgcn_mfma_f32_16x16x32_f16(AF[mf], bc0[f], acc0[mf][f], 0, 0, 0); \
      if constexpr (DUAL) \
        acc1[mf][f] = __builtin_amdgcn_mfma_f32_16x16x32_f16(AF[mf], bc1[f], acc1[mf][f], 0, 0, 0); \
    } } }

  loadB(0);
  LOADAF(0, afA)
  for (int t = 0; t < NK; t += 2) {
    cvtB();                     // waits tile-t B loads (reg deps)
    loadB(t + 1);               // next tile in flight during MFMA
    DOMFMA(afA)
    LOADAF(t + 1, afB)
    cvtB();                     // waits tile t+1 B loads
    if (t + 2 < NK) loadB(t + 2);
    DOMFMA(afB)
    if (t + 2 < NK) LOADAF(t + 2, afA)
  }
#undef LOADAF
#undef DOMFMA

  // epilogue
  int koff = (lane >> 4) << 2;
  if constexpr (MODE == 0) {
    char* Hb = (char*)outp + (size_t)e * 1048576;
#pragma unroll
    for (int mf = 0; mf < MF; mf++)
#pragma unroll
      for (int j = 0; j < 4; j++) {
        int slot = wv * 128 + mf * 16 + koff + j;
#pragma unroll
        for (int f = 0; f < NF; f++) {
          int col = n0 + f * 16 + (lane & 15);
          float g = acc0[mf][f][j], u = acc1[mf][f][j];
          float val = g / (1.f + expf(-g)) * u;
          *(f16*)(Hb + (size_t)(col >> 5) * 32768 + slot * 64 + (col & 31) * 2) = (f16)val;
        }
      }
  } else if constexpr (MODE == 1) {
    char* Hb = (char*)outp;
#pragma unroll
    for (int mf = 0; mf < MF; mf++)
#pragma unroll
      for (int j = 0; j < 4; j++) {
        int row = m0 + wv * 64 + mf * 16 + koff + j;
#pragma unroll
        for (int f = 0; f < NF; f++) {
          int col = n0 + f * 16 + (lane & 15);
          float g = acc0[mf][f][j], u = acc1[mf][f][j];
          float val = g / (1.f + expf(-g)) * u;
          *(f16*)(Hb + (size_t)(col >> 5) * 131072 + row * 64 + (col & 31) * 2) = (f16)val;
        }
      }
  } else if constexpr (MODE == 2) {
    float* Of = (float*)outp;
    const int* tokp = tokL + e * CAP;
    const float* wtp = wtL + e * CAP;
#pragma unroll
    for (int mf = 0; mf < MF; mf++)
#pragma unroll
      for (int j = 0; j < 4; j++) {
        int slot = wv * 128 + mf * 16 + koff + j;
        if (slot < Mcur) {
          int tk = tokp[slot];
          float w = wtp[slot];
#pragma unroll
          for (int f = 0; f < NF; f++) {
            int col = n0 + f * 16 + (lane & 15);
            atomicAdd(Of + (size_t)tk * HDIM + col, acc0[mf][f][j] * w);
          }
        }
      }
  } else {
    float* Of = (float*)outp;
#pragma unroll
    for (int mf = 0; mf < MF; mf++)
#pragma unroll
      for (int j = 0; j < 4; j++) {
        int row = m0 + wv * 64 + mf * 16 + koff + j;
#pragma unroll
        for (int f = 0; f < NF; f++) {
          int col = n0 + f * 16 + (lane & 15);
          Of[(size_t)row * HDIM + col] = acc0[mf][f][j];
        }
      }
  }
}

// ---------------- launch ----------------
extern "C" void kernel_launch(void* const* d_in, const int* in_sizes, int n_in,
                              void* d_out, int out_size, void* d_ws, size_t ws_size,
                              hipStream_t stream) {
  const float* x  = (const float*)d_in[0];
  const float* gw = (const float*)d_in[1];
  const float* gb = (const float*)d_in[2];
  const float* w1 = (const float*)d_in[3];
  const float* w2 = (const float*)d_in[4];
  const float* w3 = (const float*)d_in[5];
  const float* sg = (const float*)d_in[6];
  const float* su = (const float*)d_in[7];
  const float* sd = (const float*)d_in[8];
  float* out = (float*)d_out;
  char* ws = (char*)d_ws;

  f16*   xbt = (f16*)(ws);                 // 8 MB  k-chunked x fp16
  f16*   hs  = (f16*)(ws + 8388608);       // 8 MB  k-chunked shared-mid
  f16*   hbuf= (f16*)(ws + 16777216);      // 32 MB k-chunked routed-mid
  f16*   xg  = (f16*)(ws + 50331648);      // 64 MB compact gathered A
  int*   tok = (int*)(ws + 117440512);
  float* wt  = (float*)(ws + 117506048);
  int*   tidx= (int*)(ws + 117571584);
  float* tw  = (float*)(ws + 117604352);
  int*   cnt = (int*)(ws + 117637120);

  convert_kernel<<<2048, 256, 0, stream>>>(x, xbt);
  gate_kernel<<<2048, 256, 0, stream>>>(x, gw, gb, tidx, tw);
  dispatch_kernel<<<32, 256, 0, stream>>>(tidx, tw, tok, wt, cnt);
  gather_kernel<<<2048, 256, 0, stream>>>(xbt, tok, cnt, xg);

  // routed up: hbuf = silu(Xg@w1)*(Xg@w3)   grid = 32e x 32n
  gemm_kernel<0><<<1024, 256, 0, stream>>>(xg, w1, w3, hbuf, tok, wt, cnt);
  // shared up: hs = silu(x@sg)*(x@su)       grid = 8m x 64n
  gemm_kernel<1><<<512, 256, 0, stream>>>(xbt, sg, su, hs, nullptr, nullptr, nullptr);
  // shared down: out = hs @ sd              grid = 8m x 64n
  gemm_kernel<3><<<512, 256, 0, stream>>>(hs, sd, nullptr, out, nullptr, nullptr, nullptr);
  // routed down: out += w * (hbuf @ w2)     grid = 32e x 64n
  gemm_kernel<2><<<2048, 256, 0, stream>>>(hbuf, w2, nullptr, out, tok, wt, cnt);
}